// Round 1
// baseline (784.933 us; speedup 1.0000x reference)
//
#include <hip/hip_runtime.h>
#include <hip/hip_bf16.h>

#define N_NODES 30000
#define N_EDGES 480000
#define N_GRAPH 64
#define L_TOK   20
#define D_EMB   32
#define S_SCAL  64
#define TOT     224      // S + 5*D
#define H1      4
#define C1      128
#define F1      512      // H1*C1
#define F2      128
#define E_TOT   (N_EDGES + N_NODES)

// ---------------- CSR build ----------------
__global__ void init_deg(int* deg) {
    int i = blockIdx.x * blockDim.x + threadIdx.x;
    if (i < N_NODES) deg[i] = 1;   // self loop
}

__global__ void add_deg(const int* __restrict__ ei, int* deg) {
    int e = blockIdx.x * blockDim.x + threadIdx.x;
    if (e < N_EDGES) atomicAdd(&deg[ei[N_EDGES + e]], 1);
}

// single-block exclusive scan (N=30000), writes rowptr and cursor (cursor aliases deg safely)
__global__ void scan_deg(const int* __restrict__ deg, int* rowptr, int* cursor) {
    __shared__ int sh[1024];
    __shared__ int carry;
    if (threadIdx.x == 0) carry = 0;
    __syncthreads();
    for (int base = 0; base < N_NODES; base += 1024) {
        int i = base + threadIdx.x;
        int v = (i < N_NODES) ? deg[i] : 0;
        sh[threadIdx.x] = v;
        __syncthreads();
        for (int off = 1; off < 1024; off <<= 1) {
            int t = (threadIdx.x >= off) ? sh[threadIdx.x - off] : 0;
            __syncthreads();
            sh[threadIdx.x] += t;
            __syncthreads();
        }
        int incl = sh[threadIdx.x];
        int excl = incl - v;
        if (i < N_NODES) { rowptr[i] = carry + excl; cursor[i] = carry + excl; }
        __syncthreads();
        if (threadIdx.x == 1023) carry += incl;
        __syncthreads();
    }
    if (threadIdx.x == 0) rowptr[N_NODES] = carry;
}

__global__ void scatter_edges(const int* __restrict__ ei, int* cursor, int* csr_src) {
    int e = blockIdx.x * blockDim.x + threadIdx.x;
    if (e < N_EDGES) {
        int src = ei[e], dst = ei[N_EDGES + e];
        int pos = atomicAdd(&cursor[dst], 1);
        csr_src[pos] = src;
    } else if (e < E_TOT) {
        int n = e - N_EDGES;
        int pos = atomicAdd(&cursor[n], 1);
        csr_src[pos] = n;
    }
}

// ---------------- features + layernorm ----------------
__global__ void feat_ln(const float* __restrict__ xs,
                        const int* __restrict__ xo, const int* __restrict__ xsrc,
                        const int* __restrict__ xsink, const int* __restrict__ xstr,
                        const int* __restrict__ xpay,
                        const float* __restrict__ eo, const float* __restrict__ es,
                        const float* __restrict__ ek, const float* __restrict__ eg,
                        const float* __restrict__ ep,
                        const float* __restrict__ lns, const float* __restrict__ lnb,
                        float* __restrict__ x0) {
    int n = blockIdx.x, tid = threadIdx.x;   // 256 threads
    float f = 0.f;
    if (tid < S_SCAL) {
        f = xs[(size_t)n * S_SCAL + tid];
    } else if (tid < TOT) {
        int t = tid - S_SCAL;
        int ti = t >> 5, dim = t & 31;
        const int* idx; const float* emb;
        switch (ti) {
            case 0: idx = xo;   emb = eo; break;
            case 1: idx = xsrc; emb = es; break;
            case 2: idx = xsink;emb = ek; break;
            case 3: idx = xstr; emb = eg; break;
            default:idx = xpay; emb = ep; break;
        }
        float s = 0.f, cnt = 0.f;
        #pragma unroll
        for (int l = 0; l < L_TOK; ++l) {
            int id = idx[n * L_TOK + l];
            if (id != 0) { s += emb[id * D_EMB + dim]; cnt += 1.f; }
        }
        f = s / (cnt + 1e-9f);
    }
    __shared__ float red[256];
    red[tid] = (tid < TOT) ? f : 0.f;
    __syncthreads();
    for (int off = 128; off; off >>= 1) { if (tid < off) red[tid] += red[tid + off]; __syncthreads(); }
    float mu = red[0] / (float)TOT;
    __syncthreads();
    float dv = (tid < TOT) ? (f - mu) : 0.f;
    red[tid] = dv * dv;
    __syncthreads();
    for (int off = 128; off; off >>= 1) { if (tid < off) red[tid] += red[tid + off]; __syncthreads(); }
    float var = red[0] / (float)TOT;
    if (tid < TOT)
        x0[(size_t)n * TOT + tid] = (f - mu) * rsqrtf(var + 1e-5f) * lns[tid] + lnb[tid];
}

// ---------------- fp32 tiled GEMM: C[M,N] = A[M,K] @ B[K,N] ----------------
// BM=BN=64, BK=16, 256 threads, 4x4 per thread. K % 16 == 0, N % 64 == 0.
__global__ void gemm_f32(const float* __restrict__ A, const float* __restrict__ B,
                         float* __restrict__ C, int M, int N, int K) {
    __shared__ float As[16][65];
    __shared__ float Bs[16][65];
    int tid = threadIdx.x;
    int tx = tid & 15, ty = tid >> 4;
    int bm = blockIdx.x * 64, bn = blockIdx.y * 64;
    float acc[4][4] = {};
    for (int k0 = 0; k0 < K; k0 += 16) {
        // A tile: 64 rows x 16 k; thread t loads float4: row=t>>2, kq=(t&3)*4
        {
            int row = tid >> 2, kq = (tid & 3) * 4;
            float4 v = make_float4(0.f, 0.f, 0.f, 0.f);
            if (bm + row < M)
                v = *reinterpret_cast<const float4*>(&A[(size_t)(bm + row) * K + k0 + kq]);
            As[kq + 0][row] = v.x; As[kq + 1][row] = v.y;
            As[kq + 2][row] = v.z; As[kq + 3][row] = v.w;
        }
        // B tile: 16 k x 64 cols; thread t: k=t>>4, col4=(t&15)*4
        {
            int k = tid >> 4, c4 = (tid & 15) * 4;
            float4 v = *reinterpret_cast<const float4*>(&B[(size_t)(k0 + k) * N + bn + c4]);
            Bs[k][c4 + 0] = v.x; Bs[k][c4 + 1] = v.y;
            Bs[k][c4 + 2] = v.z; Bs[k][c4 + 3] = v.w;
        }
        __syncthreads();
        #pragma unroll
        for (int kk = 0; kk < 16; ++kk) {
            float a0 = As[kk][ty * 4 + 0], a1 = As[kk][ty * 4 + 1];
            float a2 = As[kk][ty * 4 + 2], a3 = As[kk][ty * 4 + 3];
            float b0 = Bs[kk][tx * 4 + 0], b1 = Bs[kk][tx * 4 + 1];
            float b2 = Bs[kk][tx * 4 + 2], b3 = Bs[kk][tx * 4 + 3];
            acc[0][0] += a0 * b0; acc[0][1] += a0 * b1; acc[0][2] += a0 * b2; acc[0][3] += a0 * b3;
            acc[1][0] += a1 * b0; acc[1][1] += a1 * b1; acc[1][2] += a1 * b2; acc[1][3] += a1 * b3;
            acc[2][0] += a2 * b0; acc[2][1] += a2 * b1; acc[2][2] += a2 * b2; acc[2][3] += a2 * b3;
            acc[3][0] += a3 * b0; acc[3][1] += a3 * b1; acc[3][2] += a3 * b2; acc[3][3] += a3 * b3;
        }
        __syncthreads();
    }
    #pragma unroll
    for (int i = 0; i < 4; ++i) {
        int row = bm + ty * 4 + i;
        if (row < M) {
            #pragma unroll
            for (int j = 0; j < 4; ++j)
                C[(size_t)row * N + bn + tx * 4 + j] = acc[i][j];
        }
    }
}

// ---------------- attention prep ----------------
__global__ void att_prep1(const float* __restrict__ h1, const float* __restrict__ asrc,
                          const float* __restrict__ adst, float* __restrict__ s1,
                          float* __restrict__ d1) {
    int n = blockIdx.x, tid = threadIdx.x;  // 512 threads
    float h = h1[(size_t)n * F1 + tid];
    float sv = h * asrc[tid], dv = h * adst[tid];
    for (int off = 32; off; off >>= 1) { sv += __shfl_down(sv, off); dv += __shfl_down(dv, off); }
    __shared__ float ssh[8], dsh[8];
    if ((tid & 63) == 0) { ssh[tid >> 6] = sv; dsh[tid >> 6] = dv; }
    __syncthreads();
    if (tid < H1) {
        s1[n * H1 + tid] = ssh[2 * tid] + ssh[2 * tid + 1];
        d1[n * H1 + tid] = dsh[2 * tid] + dsh[2 * tid + 1];
    }
}

__global__ void att_prep2(const float* __restrict__ h2, const float* __restrict__ asrc,
                          const float* __restrict__ adst, float* __restrict__ s2,
                          float* __restrict__ d2) {
    int n = blockIdx.x, tid = threadIdx.x;  // 128 threads
    float h = h2[(size_t)n * F2 + tid];
    float sv = h * asrc[tid], dv = h * adst[tid];
    for (int off = 32; off; off >>= 1) { sv += __shfl_down(sv, off); dv += __shfl_down(dv, off); }
    __shared__ float ssh[2], dsh[2];
    if ((tid & 63) == 0) { ssh[tid >> 6] = sv; dsh[tid >> 6] = dv; }
    __syncthreads();
    if (tid == 0) { s2[n] = ssh[0] + ssh[1]; d2[n] = dsh[0] + dsh[1]; }
}

// ---------------- GAT layer 1: softmax + aggregate + bias + elu ----------------
__global__ void gat1_aggregate(const float* __restrict__ h1, const float* __restrict__ s1,
                               const float* __restrict__ d1, const int* __restrict__ rowptr,
                               const int* __restrict__ csr, const float* __restrict__ b1,
                               float* __restrict__ x1) {
    int n = blockIdx.x, tid = threadIdx.x;    // 256 threads: wave w handles head w in phases 1-2
    int wave = tid >> 6, lane = tid & 63;
    int r0 = rowptr[n], deg = rowptr[n + 1] - r0;
    __shared__ float m_sh[H1], den_sh[H1], d_n[H1];
    if (tid < H1) d_n[tid] = d1[n * H1 + tid];
    __syncthreads();
    // phase 1: per-head max
    float m = -1e30f;
    for (int i = lane; i < deg; i += 64) {
        int src = csr[r0 + i];
        float e = s1[src * H1 + wave] + d_n[wave];
        e = (e >= 0.f) ? e : 0.2f * e;
        m = fmaxf(m, e);
    }
    for (int off = 32; off; off >>= 1) m = fmaxf(m, __shfl_down(m, off));
    if (lane == 0) m_sh[wave] = m;
    __syncthreads();
    // phase 2: per-head denom
    float mh = m_sh[wave];
    float den = 0.f;
    for (int i = lane; i < deg; i += 64) {
        int src = csr[r0 + i];
        float e = s1[src * H1 + wave] + d_n[wave];
        e = (e >= 0.f) ? e : 0.2f * e;
        den += __expf(e - mh);
    }
    for (int off = 32; off; off >>= 1) den += __shfl_down(den, off);
    if (lane == 0) den_sh[wave] = den;
    __syncthreads();
    // phase 3: aggregate 2 channels per thread (tid and tid+256)
    int ha = tid >> 7, hb = (tid + 256) >> 7;
    float dna = d_n[ha], dnb = d_n[hb];
    float ma = m_sh[ha], mb = m_sh[hb];
    float inva = 1.f / den_sh[ha], invb = 1.f / den_sh[hb];
    float acc0 = 0.f, acc1 = 0.f;
    for (int i = 0; i < deg; ++i) {
        int src = csr[r0 + i];
        float ea = s1[src * H1 + ha] + dna; ea = (ea >= 0.f) ? ea : 0.2f * ea;
        float eb = s1[src * H1 + hb] + dnb; eb = (eb >= 0.f) ? eb : 0.2f * eb;
        float aa = __expf(ea - ma) * inva;
        float ab = __expf(eb - mb) * invb;
        acc0 += aa * h1[(size_t)src * F1 + tid];
        acc1 += ab * h1[(size_t)src * F1 + tid + 256];
    }
    float v0 = acc0 + b1[tid];       v0 = (v0 > 0.f) ? v0 : expm1f(v0);
    float v1 = acc1 + b1[tid + 256]; v1 = (v1 > 0.f) ? v1 : expm1f(v1);
    x1[(size_t)n * F1 + tid] = v0;
    x1[(size_t)n * F1 + tid + 256] = v1;
}

// ---------------- GAT layer 2 + elu + graph max-pool ----------------
__device__ __forceinline__ unsigned int f2ord(float f) {
    unsigned int b = __float_as_uint(f);
    return (b & 0x80000000u) ? ~b : (b | 0x80000000u);
}

__global__ void pool_init(unsigned int* pool) {
    int i = blockIdx.x * blockDim.x + threadIdx.x;
    if (i < N_GRAPH * F2) pool[i] = 0x007FFFFFu;   // f2ord(-inf)
}

__global__ void gat2_pool(const float* __restrict__ h2, const float* __restrict__ s2,
                          const float* __restrict__ d2, const int* __restrict__ rowptr,
                          const int* __restrict__ csr, const float* __restrict__ b2,
                          const int* __restrict__ batch, unsigned int* __restrict__ pool) {
    int n = blockIdx.x, tid = threadIdx.x;   // 128 threads
    int r0 = rowptr[n], deg = rowptr[n + 1] - r0;
    __shared__ float sh[2];
    __shared__ float m_s, den_s;
    float dn = d2[n];
    float m = -1e30f;
    for (int i = tid; i < deg; i += 128) {
        float e = s2[csr[r0 + i]] + dn; e = (e >= 0.f) ? e : 0.2f * e;
        m = fmaxf(m, e);
    }
    for (int off = 32; off; off >>= 1) m = fmaxf(m, __shfl_down(m, off));
    if ((tid & 63) == 0) sh[tid >> 6] = m;
    __syncthreads();
    if (tid == 0) m_s = fmaxf(sh[0], sh[1]);
    __syncthreads();
    float mm = m_s;
    float den = 0.f;
    for (int i = tid; i < deg; i += 128) {
        float e = s2[csr[r0 + i]] + dn; e = (e >= 0.f) ? e : 0.2f * e;
        den += __expf(e - mm);
    }
    for (int off = 32; off; off >>= 1) den += __shfl_down(den, off);
    if ((tid & 63) == 0) sh[tid >> 6] = den;
    __syncthreads();
    if (tid == 0) den_s = sh[0] + sh[1];
    __syncthreads();
    float inv = 1.f / den_s;
    float acc = 0.f;
    for (int i = 0; i < deg; ++i) {
        int src = csr[r0 + i];
        float e = s2[src] + dn; e = (e >= 0.f) ? e : 0.2f * e;
        acc += __expf(e - mm) * inv * h2[(size_t)src * F2 + tid];
    }
    float v = acc + b2[tid];
    v = (v > 0.f) ? v : expm1f(v);
    atomicMax(&pool[batch[n] * F2 + tid], f2ord(v));
}

__global__ void pool_finalize(const unsigned int* __restrict__ pool, float* __restrict__ out) {
    int i = blockIdx.x * blockDim.x + threadIdx.x;
    if (i < N_GRAPH * F2) {
        unsigned int k = pool[i];
        unsigned int b = (k & 0x80000000u) ? (k ^ 0x80000000u) : ~k;
        out[i] = __uint_as_float(b);
    }
}

// ---------------- launcher ----------------
extern "C" void kernel_launch(void* const* d_in, const int* in_sizes, int n_in,
                              void* d_out, int out_size, void* d_ws, size_t ws_size,
                              hipStream_t stream) {
    const float* x_scalar = (const float*)d_in[0];
    const int*   x_opcode = (const int*)d_in[1];
    const int*   x_source = (const int*)d_in[2];
    const int*   x_sink   = (const int*)d_in[3];
    const int*   x_string = (const int*)d_in[4];
    const int*   x_payload= (const int*)d_in[5];
    const int*   edge_idx = (const int*)d_in[6];
    const int*   batch    = (const int*)d_in[7];
    const float* emb_op   = (const float*)d_in[8];
    const float* emb_src  = (const float*)d_in[9];
    const float* emb_snk  = (const float*)d_in[10];
    const float* emb_str  = (const float*)d_in[11];
    const float* emb_pay  = (const float*)d_in[12];
    const float* ln_scale = (const float*)d_in[13];
    const float* ln_bias  = (const float*)d_in[14];
    const float* W1       = (const float*)d_in[15];
    const float* att_src1 = (const float*)d_in[16];
    const float* att_dst1 = (const float*)d_in[17];
    const float* b1       = (const float*)d_in[18];
    const float* W2       = (const float*)d_in[19];
    const float* att_src2 = (const float*)d_in[20];
    const float* att_dst2 = (const float*)d_in[21];
    const float* b2       = (const float*)d_in[22];
    float* out = (float*)d_out;

    // workspace layout (floats)
    float* x0 = (float*)d_ws;                 // N*224
    float* h1 = x0 + (size_t)N_NODES * TOT;   // N*512
    float* x1 = h1 + (size_t)N_NODES * F1;    // N*512
    float* s1 = x1 + (size_t)N_NODES * F1;    // N*4
    float* d1 = s1 + (size_t)N_NODES * H1;    // N*4
    float* s2 = d1 + (size_t)N_NODES * H1;    // N
    float* d2 = s2 + N_NODES;                 // N
    int* rowptr = (int*)(d2 + N_NODES);       // N+1
    int* cursor = rowptr + (N_NODES + 1);     // N+1 (also deg)
    int* csr    = cursor + (N_NODES + 1);     // E_TOT
    unsigned int* pool = (unsigned int*)(csr + E_TOT); // G*128
    float* h2 = x0;                           // alias: x0 dead after GEMM1

    // CSR build
    init_deg<<<(N_NODES + 255) / 256, 256, 0, stream>>>(cursor);
    add_deg<<<(N_EDGES + 255) / 256, 256, 0, stream>>>(edge_idx, cursor);
    scan_deg<<<1, 1024, 0, stream>>>(cursor, rowptr, cursor);
    scatter_edges<<<(E_TOT + 255) / 256, 256, 0, stream>>>(edge_idx, cursor, csr);

    // features + LN
    feat_ln<<<N_NODES, 256, 0, stream>>>(x_scalar, x_opcode, x_source, x_sink, x_string,
                                         x_payload, emb_op, emb_src, emb_snk, emb_str,
                                         emb_pay, ln_scale, ln_bias, x0);

    // layer 1
    dim3 g1((N_NODES + 63) / 64, F1 / 64);
    gemm_f32<<<g1, 256, 0, stream>>>(x0, W1, h1, N_NODES, F1, TOT);
    att_prep1<<<N_NODES, 512, 0, stream>>>(h1, att_src1, att_dst1, s1, d1);
    gat1_aggregate<<<N_NODES, 256, 0, stream>>>(h1, s1, d1, rowptr, csr, b1, x1);

    // layer 2
    dim3 g2((N_NODES + 63) / 64, F2 / 64);
    gemm_f32<<<g2, 256, 0, stream>>>(x1, W2, h2, N_NODES, F2, F1);
    att_prep2<<<N_NODES, 128, 0, stream>>>(h2, att_src2, att_dst2, s2, d2);

    pool_init<<<(N_GRAPH * F2 + 255) / 256, 256, 0, stream>>>(pool);
    gat2_pool<<<N_NODES, 128, 0, stream>>>(h2, s2, d2, rowptr, csr, b2, batch, pool);
    pool_finalize<<<(N_GRAPH * F2 + 255) / 256, 256, 0, stream>>>(pool, out);
}

// Round 2
// 503.846 us; speedup vs baseline: 1.5579x; 1.5579x over previous
//
#include <hip/hip_runtime.h>
#include <hip/hip_bf16.h>

#define N_NODES 30000
#define M_PAD   30016     // 469*64
#define N_EDGES 480000
#define N_GRAPH 64
#define L_TOK   20
#define D_EMB   32
#define S_SCAL  64
#define TOT     224      // S + 5*D, = 7*32
#define H1      4
#define C1      128
#define F1      512      // H1*C1
#define F2      128
#define E_TOT   (N_EDGES + N_NODES)

typedef __attribute__((ext_vector_type(8))) short bf16x8;
typedef __attribute__((ext_vector_type(4))) float f32x4;

__device__ __forceinline__ unsigned short f2b(float f) {
    unsigned u = __float_as_uint(f);
    u += 0x7FFFu + ((u >> 16) & 1u);
    return (unsigned short)(u >> 16);
}
__device__ __forceinline__ float b2f(unsigned short h) {
    return __uint_as_float(((unsigned)h) << 16);
}

// ---------------- CSR build ----------------
__global__ void init_deg(int* deg) {
    int i = blockIdx.x * blockDim.x + threadIdx.x;
    if (i < N_NODES) deg[i] = 1;   // self loop
}

__global__ void add_deg(const int* __restrict__ ei, int* deg) {
    int e = blockIdx.x * blockDim.x + threadIdx.x;
    if (e < N_EDGES) atomicAdd(&deg[ei[N_EDGES + e]], 1);
}

__global__ void scan_deg(const int* __restrict__ deg, int* rowptr, int* cursor) {
    __shared__ int sh[1024];
    __shared__ int carry;
    if (threadIdx.x == 0) carry = 0;
    __syncthreads();
    for (int base = 0; base < N_NODES; base += 1024) {
        int i = base + threadIdx.x;
        int v = (i < N_NODES) ? deg[i] : 0;
        sh[threadIdx.x] = v;
        __syncthreads();
        for (int off = 1; off < 1024; off <<= 1) {
            int t = (threadIdx.x >= off) ? sh[threadIdx.x - off] : 0;
            __syncthreads();
            sh[threadIdx.x] += t;
            __syncthreads();
        }
        int incl = sh[threadIdx.x];
        int excl = incl - v;
        if (i < N_NODES) { rowptr[i] = carry + excl; cursor[i] = carry + excl; }
        __syncthreads();
        if (threadIdx.x == 1023) carry += incl;
        __syncthreads();
    }
    if (threadIdx.x == 0) rowptr[N_NODES] = carry;
}

__global__ void scatter_edges(const int* __restrict__ ei, int* cursor, int* csr_src) {
    int e = blockIdx.x * blockDim.x + threadIdx.x;
    if (e < N_EDGES) {
        int src = ei[e], dst = ei[N_EDGES + e];
        int pos = atomicAdd(&cursor[dst], 1);
        csr_src[pos] = src;
    } else if (e < E_TOT) {
        int n = e - N_EDGES;
        int pos = atomicAdd(&cursor[n], 1);
        csr_src[pos] = n;
    }
}

// ---------------- weight transpose+cast: WT[n*K+k] = bf16(W[k*N+n]) ----------------
__global__ void transpose_cast(const float* __restrict__ W, unsigned short* __restrict__ WT,
                               int K, int N) {
    int idx = blockIdx.x * blockDim.x + threadIdx.x;
    if (idx < K * N) {
        int n = idx / K, k = idx - n * K;
        WT[idx] = f2b(W[(size_t)k * N + n]);
    }
}

// ---------------- features + layernorm (bf16 out) ----------------
__global__ void feat_ln(const float* __restrict__ xs,
                        const int* __restrict__ xo, const int* __restrict__ xsrc,
                        const int* __restrict__ xsink, const int* __restrict__ xstr,
                        const int* __restrict__ xpay,
                        const float* __restrict__ eo, const float* __restrict__ es,
                        const float* __restrict__ ek, const float* __restrict__ eg,
                        const float* __restrict__ ep,
                        const float* __restrict__ lns, const float* __restrict__ lnb,
                        unsigned short* __restrict__ x0) {
    int n = blockIdx.x, tid = threadIdx.x;   // 256 threads
    float f = 0.f;
    if (tid < S_SCAL) {
        f = xs[(size_t)n * S_SCAL + tid];
    } else if (tid < TOT) {
        int t = tid - S_SCAL;
        int ti = t >> 5, dim = t & 31;
        const int* idx; const float* emb;
        switch (ti) {
            case 0: idx = xo;   emb = eo; break;
            case 1: idx = xsrc; emb = es; break;
            case 2: idx = xsink;emb = ek; break;
            case 3: idx = xstr; emb = eg; break;
            default:idx = xpay; emb = ep; break;
        }
        float s = 0.f, cnt = 0.f;
        #pragma unroll
        for (int l = 0; l < L_TOK; ++l) {
            int id = idx[n * L_TOK + l];
            if (id != 0) { s += emb[id * D_EMB + dim]; cnt += 1.f; }
        }
        f = s / (cnt + 1e-9f);
    }
    __shared__ float red[256];
    red[tid] = (tid < TOT) ? f : 0.f;
    __syncthreads();
    for (int off = 128; off; off >>= 1) { if (tid < off) red[tid] += red[tid + off]; __syncthreads(); }
    float mu = red[0] / (float)TOT;
    __syncthreads();
    float dv = (tid < TOT) ? (f - mu) : 0.f;
    red[tid] = dv * dv;
    __syncthreads();
    for (int off = 128; off; off >>= 1) { if (tid < off) red[tid] += red[tid + off]; __syncthreads(); }
    float var = red[0] / (float)TOT;
    if (tid < TOT)
        x0[(size_t)n * TOT + tid] = f2b((f - mu) * rsqrtf(var + 1e-5f) * lns[tid] + lnb[tid]);
}

// ---------------- bf16 MFMA GEMM: C[M,N] = A[M,K] @ BT[N,K]^T ----------------
// BM=BN=64, BK=32, 256 threads (4 waves), mfma_f32_16x16x32_bf16.
// Wave w computes rows [w*16, w*16+16) x 64 cols. K%32==0, N%64==0, A has M_PAD rows.
__global__ void gemm_bf16(const unsigned short* __restrict__ A,
                          const unsigned short* __restrict__ BT,
                          unsigned short* __restrict__ C, int M, int N, int K) {
    __shared__ unsigned short As[64][40];   // 32 k + 8 pad
    __shared__ unsigned short Bs[64][40];
    int tid = threadIdx.x;
    int wave = tid >> 6, lane = tid & 63;
    int l15 = lane & 15, kb = lane >> 4;    // kb in 0..3
    int bm = blockIdx.x * 64, bn = blockIdx.y * 64;
    f32x4 acc[4] = {};
    int row_ld = tid >> 2, seg = tid & 3;
    for (int k0 = 0; k0 < K; k0 += 32) {
        // A tile: 64 rows x 32 k
        {
            const uint4 v = *reinterpret_cast<const uint4*>(&A[(size_t)(bm + row_ld) * K + k0 + seg * 8]);
            *reinterpret_cast<uint4*>(&As[row_ld][seg * 8]) = v;
        }
        // B tile from BT: 64 n-rows x 32 k
        {
            const uint4 v = *reinterpret_cast<const uint4*>(&BT[(size_t)(bn + row_ld) * K + k0 + seg * 8]);
            *reinterpret_cast<uint4*>(&Bs[row_ld][seg * 8]) = v;
        }
        __syncthreads();
        bf16x8 af = *reinterpret_cast<const bf16x8*>(&As[wave * 16 + l15][kb * 8]);
        #pragma unroll
        for (int t = 0; t < 4; ++t) {
            bf16x8 bfr = *reinterpret_cast<const bf16x8*>(&Bs[t * 16 + l15][kb * 8]);
            acc[t] = __builtin_amdgcn_mfma_f32_16x16x32_bf16(af, bfr, acc[t], 0, 0, 0);
        }
        __syncthreads();
    }
    #pragma unroll
    for (int t = 0; t < 4; ++t) {
        #pragma unroll
        for (int r = 0; r < 4; ++r) {
            int row = bm + wave * 16 + kb * 4 + r;
            if (row < M)
                C[(size_t)row * N + bn + t * 16 + l15] = f2b(acc[t][r]);
        }
    }
}

// ---------------- attention prep ----------------
__global__ void att_prep1(const unsigned short* __restrict__ h1, const float* __restrict__ asrc,
                          const float* __restrict__ adst, float* __restrict__ s1,
                          float* __restrict__ d1) {
    int n = blockIdx.x, tid = threadIdx.x;  // 512 threads
    float h = b2f(h1[(size_t)n * F1 + tid]);
    float sv = h * asrc[tid], dv = h * adst[tid];
    for (int off = 32; off; off >>= 1) { sv += __shfl_down(sv, off); dv += __shfl_down(dv, off); }
    __shared__ float ssh[8], dsh[8];
    if ((tid & 63) == 0) { ssh[tid >> 6] = sv; dsh[tid >> 6] = dv; }
    __syncthreads();
    if (tid < H1) {
        s1[n * H1 + tid] = ssh[2 * tid] + ssh[2 * tid + 1];
        d1[n * H1 + tid] = dsh[2 * tid] + dsh[2 * tid + 1];
    }
}

__global__ void att_prep2(const unsigned short* __restrict__ h2, const float* __restrict__ asrc,
                          const float* __restrict__ adst, float* __restrict__ s2,
                          float* __restrict__ d2) {
    int n = blockIdx.x, tid = threadIdx.x;  // 128 threads
    float h = b2f(h2[(size_t)n * F2 + tid]);
    float sv = h * asrc[tid], dv = h * adst[tid];
    for (int off = 32; off; off >>= 1) { sv += __shfl_down(sv, off); dv += __shfl_down(dv, off); }
    __shared__ float ssh[2], dsh[2];
    if ((tid & 63) == 0) { ssh[tid >> 6] = sv; dsh[tid >> 6] = dv; }
    __syncthreads();
    if (tid == 0) { s2[n] = ssh[0] + ssh[1]; d2[n] = dsh[0] + dsh[1]; }
}

// ---------------- GAT layer 1: softmax + aggregate + bias + elu ----------------
__global__ void gat1_aggregate(const unsigned short* __restrict__ h1, const float* __restrict__ s1,
                               const float* __restrict__ d1, const int* __restrict__ rowptr,
                               const int* __restrict__ csr, const float* __restrict__ b1,
                               unsigned short* __restrict__ x1) {
    int n = blockIdx.x, tid = threadIdx.x;    // 256 threads; wave = head for phases 1-2
    int wave = tid >> 6, lane = tid & 63;
    int r0 = rowptr[n], deg = rowptr[n + 1] - r0;
    __shared__ float m_sh[H1], den_sh[H1], d_n[H1];
    __shared__ float alpha_sh[H1][64];
    __shared__ int src_sh[64];
    if (tid < H1) d_n[tid] = d1[n * H1 + tid];
    __syncthreads();
    float dnw = d_n[wave];
    // phase 1: per-head max
    float m = -1e30f;
    for (int i = lane; i < deg; i += 64) {
        int src = csr[r0 + i];
        float e = s1[src * H1 + wave] + dnw;
        e = (e >= 0.f) ? e : 0.2f * e;
        m = fmaxf(m, e);
    }
    for (int off = 32; off; off >>= 1) m = fmaxf(m, __shfl_down(m, off));
    if (lane == 0) m_sh[wave] = m;
    __syncthreads();
    float mh = m_sh[wave];
    // phase 2: per-head denom
    float den = 0.f;
    for (int i = lane; i < deg; i += 64) {
        int src = csr[r0 + i];
        float e = s1[src * H1 + wave] + dnw;
        e = (e >= 0.f) ? e : 0.2f * e;
        den += __expf(e - mh);
    }
    for (int off = 32; off; off >>= 1) den += __shfl_down(den, off);
    if (lane == 0) den_sh[wave] = den;
    __syncthreads();
    float invw = 1.f / den_sh[wave];
    // phase 3: chunked alpha + gather (2 channels/thread via bf16x2)
    const unsigned* h1u = (const unsigned*)h1;   // rows of 256 uints
    float2 acc = make_float2(0.f, 0.f);
    for (int c0 = 0; c0 < deg; c0 += 64) {
        __syncthreads();
        int i = c0 + lane;
        if (i < deg) {
            int src = csr[r0 + i];
            if (wave == 0) src_sh[lane] = src;
            float e = s1[src * H1 + wave] + dnw;
            e = (e >= 0.f) ? e : 0.2f * e;
            alpha_sh[wave][lane] = __expf(e - mh) * invw;
        }
        __syncthreads();
        int cnt = min(64, deg - c0);
        int hh = tid >> 6;
        for (int e = 0; e < cnt; ++e) {
            int src = src_sh[e];
            float a = alpha_sh[hh][e];
            unsigned v = h1u[(size_t)src * 256 + tid];
            acc.x += a * b2f((unsigned short)(v & 0xFFFFu));
            acc.y += a * b2f((unsigned short)(v >> 16));
        }
    }
    int c = 2 * tid;
    float v0 = acc.x + b1[c];     v0 = (v0 > 0.f) ? v0 : expm1f(v0);
    float v1 = acc.y + b1[c + 1]; v1 = (v1 > 0.f) ? v1 : expm1f(v1);
    unsigned packed = (unsigned)f2b(v0) | ((unsigned)f2b(v1) << 16);
    ((unsigned*)x1)[(size_t)n * 256 + tid] = packed;
}

// ---------------- GAT layer 2 + elu + graph max-pool ----------------
__device__ __forceinline__ unsigned int f2ord(float f) {
    unsigned int b = __float_as_uint(f);
    return (b & 0x80000000u) ? ~b : (b | 0x80000000u);
}

__global__ void pool_init(unsigned int* pool) {
    int i = blockIdx.x * blockDim.x + threadIdx.x;
    if (i < N_GRAPH * F2) pool[i] = 0x007FFFFFu;   // f2ord(-inf)
}

__global__ void gat2_pool(const unsigned short* __restrict__ h2, const float* __restrict__ s2,
                          const float* __restrict__ d2, const int* __restrict__ rowptr,
                          const int* __restrict__ csr, const float* __restrict__ b2,
                          const int* __restrict__ batch, unsigned int* __restrict__ pool) {
    int n = blockIdx.x, tid = threadIdx.x;   // 128 threads
    int r0 = rowptr[n], deg = rowptr[n + 1] - r0;
    __shared__ float sh[2];
    __shared__ float m_s, den_s;
    __shared__ float alpha_sh[128];
    __shared__ int src_sh[128];
    float dn = d2[n];
    float m = -1e30f;
    for (int i = tid; i < deg; i += 128) {
        float e = s2[csr[r0 + i]] + dn; e = (e >= 0.f) ? e : 0.2f * e;
        m = fmaxf(m, e);
    }
    for (int off = 32; off; off >>= 1) m = fmaxf(m, __shfl_down(m, off));
    if ((tid & 63) == 0) sh[tid >> 6] = m;
    __syncthreads();
    if (tid == 0) m_s = fmaxf(sh[0], sh[1]);
    __syncthreads();
    float mm = m_s;
    float den = 0.f;
    for (int i = tid; i < deg; i += 128) {
        float e = s2[csr[r0 + i]] + dn; e = (e >= 0.f) ? e : 0.2f * e;
        den += __expf(e - mm);
    }
    for (int off = 32; off; off >>= 1) den += __shfl_down(den, off);
    if ((tid & 63) == 0) sh[tid >> 6] = den;
    __syncthreads();
    if (tid == 0) den_s = sh[0] + sh[1];
    __syncthreads();
    float inv = 1.f / den_s;
    float acc = 0.f;
    for (int c0 = 0; c0 < deg; c0 += 128) {
        __syncthreads();
        int i = c0 + tid;
        if (i < deg) {
            int src = csr[r0 + i];
            src_sh[tid] = src;
            float e = s2[src] + dn; e = (e >= 0.f) ? e : 0.2f * e;
            alpha_sh[tid] = __expf(e - mm) * inv;
        }
        __syncthreads();
        int cnt = min(128, deg - c0);
        for (int e = 0; e < cnt; ++e)
            acc += alpha_sh[e] * b2f(h2[(size_t)src_sh[e] * F2 + tid]);
    }
    float v = acc + b2[tid];
    v = (v > 0.f) ? v : expm1f(v);
    atomicMax(&pool[batch[n] * F2 + tid], f2ord(v));
}

__global__ void pool_finalize(const unsigned int* __restrict__ pool, float* __restrict__ out) {
    int i = blockIdx.x * blockDim.x + threadIdx.x;
    if (i < N_GRAPH * F2) {
        unsigned int k = pool[i];
        unsigned int b = (k & 0x80000000u) ? (k ^ 0x80000000u) : ~k;
        out[i] = __uint_as_float(b);
    }
}

// ---------------- launcher ----------------
extern "C" void kernel_launch(void* const* d_in, const int* in_sizes, int n_in,
                              void* d_out, int out_size, void* d_ws, size_t ws_size,
                              hipStream_t stream) {
    const float* x_scalar = (const float*)d_in[0];
    const int*   x_opcode = (const int*)d_in[1];
    const int*   x_source = (const int*)d_in[2];
    const int*   x_sink   = (const int*)d_in[3];
    const int*   x_string = (const int*)d_in[4];
    const int*   x_payload= (const int*)d_in[5];
    const int*   edge_idx = (const int*)d_in[6];
    const int*   batch    = (const int*)d_in[7];
    const float* emb_op   = (const float*)d_in[8];
    const float* emb_src  = (const float*)d_in[9];
    const float* emb_snk  = (const float*)d_in[10];
    const float* emb_str  = (const float*)d_in[11];
    const float* emb_pay  = (const float*)d_in[12];
    const float* ln_scale = (const float*)d_in[13];
    const float* ln_bias  = (const float*)d_in[14];
    const float* W1       = (const float*)d_in[15];
    const float* att_src1 = (const float*)d_in[16];
    const float* att_dst1 = (const float*)d_in[17];
    const float* b1       = (const float*)d_in[18];
    const float* W2       = (const float*)d_in[19];
    const float* att_src2 = (const float*)d_in[20];
    const float* att_dst2 = (const float*)d_in[21];
    const float* b2       = (const float*)d_in[22];
    float* out = (float*)d_out;

    // workspace layout
    unsigned short* x0  = (unsigned short*)d_ws;               // M_PAD*224 bf16
    unsigned short* h1  = x0 + (size_t)M_PAD * TOT;            // M_PAD*512
    unsigned short* x1  = h1 + (size_t)M_PAD * F1;             // M_PAD*512
    unsigned short* h2  = x1 + (size_t)M_PAD * F1;             // M_PAD*128
    unsigned short* W1T = h2 + (size_t)M_PAD * F2;             // 512*224
    unsigned short* W2T = W1T + (size_t)F1 * TOT;              // 128*512
    float* s1 = (float*)(W2T + (size_t)F2 * F1);               // N*4
    float* d1 = s1 + (size_t)N_NODES * H1;
    float* s2 = d1 + (size_t)N_NODES * H1;                     // N
    float* d2 = s2 + N_NODES;
    int* rowptr = (int*)(d2 + N_NODES);                        // N+1
    int* cursor = rowptr + (N_NODES + 1);                      // N+1
    int* csr    = cursor + (N_NODES + 1);                      // E_TOT
    unsigned int* pool = (unsigned int*)(csr + E_TOT);         // G*128

    // CSR build
    init_deg<<<(N_NODES + 255) / 256, 256, 0, stream>>>(cursor);
    add_deg<<<(N_EDGES + 255) / 256, 256, 0, stream>>>(edge_idx, cursor);
    scan_deg<<<1, 1024, 0, stream>>>(cursor, rowptr, cursor);
    scatter_edges<<<(E_TOT + 255) / 256, 256, 0, stream>>>(edge_idx, cursor, csr);

    // weight transposes
    transpose_cast<<<(TOT * F1 + 255) / 256, 256, 0, stream>>>(W1, W1T, TOT, F1);
    transpose_cast<<<(F1 * F2 + 255) / 256, 256, 0, stream>>>(W2, W2T, F1, F2);

    // features + LN
    feat_ln<<<N_NODES, 256, 0, stream>>>(x_scalar, x_opcode, x_source, x_sink, x_string,
                                         x_payload, emb_op, emb_src, emb_snk, emb_str,
                                         emb_pay, ln_scale, ln_bias, x0);

    // layer 1
    dim3 g1(M_PAD / 64, F1 / 64);
    gemm_bf16<<<g1, 256, 0, stream>>>(x0, W1T, h1, N_NODES, F1, TOT);
    att_prep1<<<N_NODES, 512, 0, stream>>>(h1, att_src1, att_dst1, s1, d1);
    gat1_aggregate<<<N_NODES, 256, 0, stream>>>(h1, s1, d1, rowptr, csr, b1, x1);

    // layer 2
    dim3 g2(M_PAD / 64, F2 / 64);
    gemm_bf16<<<g2, 256, 0, stream>>>(x1, W2T, h2, N_NODES, F2, F1);
    att_prep2<<<N_NODES, 128, 0, stream>>>(h2, att_src2, att_dst2, s2, d2);

    pool_init<<<(N_GRAPH * F2 + 255) / 256, 256, 0, stream>>>(pool);
    gat2_pool<<<N_NODES, 128, 0, stream>>>(h2, s2, d2, rowptr, csr, b2, batch, pool);
    pool_finalize<<<(N_GRAPH * F2 + 255) / 256, 256, 0, stream>>>(pool, out);
}

// Round 3
// 407.365 us; speedup vs baseline: 1.9269x; 1.2368x over previous
//
#include <hip/hip_runtime.h>
#include <hip/hip_bf16.h>

#define N_NODES 30000
#define M_PAD   30016     // 469*64
#define N_EDGES 480000
#define N_GRAPH 64
#define L_TOK   20
#define D_EMB   32
#define S_SCAL  64
#define TOT     224      // S + 5*D, = 7*32
#define H1      4
#define C1      128
#define F1      512      // H1*C1
#define F2      128
#define E_TOT   (N_EDGES + N_NODES)

typedef __attribute__((ext_vector_type(8))) short bf16x8;
typedef __attribute__((ext_vector_type(4))) float f32x4;

__device__ __forceinline__ unsigned short f2b(float f) {
    unsigned u = __float_as_uint(f);
    u += 0x7FFFu + ((u >> 16) & 1u);
    return (unsigned short)(u >> 16);
}
__device__ __forceinline__ float b2f(unsigned short h) {
    return __uint_as_float(((unsigned)h) << 16);
}

// ---------------- CSR build ----------------
__global__ void init_deg(int* deg) {
    int i = blockIdx.x * blockDim.x + threadIdx.x;
    if (i < N_NODES) deg[i] = 1;   // self loop
}

__global__ void add_deg(const int* __restrict__ ei, int* deg) {
    int e = blockIdx.x * blockDim.x + threadIdx.x;
    if (e < N_EDGES) atomicAdd(&deg[ei[N_EDGES + e]], 1);
}

// single block, 1024 threads; thread t serially scans elements [t*30, t*30+30)
#define SCAN_PER 30
__global__ void scan_deg(const int* __restrict__ deg, int* __restrict__ rowptr,
                         int* __restrict__ cursor) {
    int t = threadIdx.x, lane = t & 63, wid = t >> 6;   // 16 waves
    int base = t * SCAN_PER;
    int v[SCAN_PER];
    int lsum = 0;
    #pragma unroll
    for (int i = 0; i < SCAN_PER; ++i) {
        int ii = base + i;
        int d = (ii < N_NODES) ? deg[ii] : 0;
        v[i] = lsum;            // local exclusive prefix
        lsum += d;
    }
    int incl = lsum;
    #pragma unroll
    for (int off = 1; off < 64; off <<= 1) {
        int u = __shfl_up(incl, off);
        if (lane >= off) incl += u;
    }
    __shared__ int wsum[16], woff[16];
    if (lane == 63) wsum[wid] = incl;
    __syncthreads();
    if (t == 0) {
        int run = 0;
        #pragma unroll
        for (int w = 0; w < 16; ++w) { woff[w] = run; run += wsum[w]; }
        rowptr[N_NODES] = run;
    }
    __syncthreads();
    int texcl = woff[wid] + (incl - lsum);
    #pragma unroll
    for (int i = 0; i < SCAN_PER; ++i) {
        int ii = base + i;
        if (ii < N_NODES) { int p = texcl + v[i]; rowptr[ii] = p; cursor[ii] = p; }
    }
}

__global__ void scatter_edges(const int* __restrict__ ei, int* cursor, int* csr_src) {
    int e = blockIdx.x * blockDim.x + threadIdx.x;
    if (e < N_EDGES) {
        int src = ei[e], dst = ei[N_EDGES + e];
        int pos = atomicAdd(&cursor[dst], 1);
        csr_src[pos] = src;
    } else if (e < E_TOT) {
        int n = e - N_EDGES;
        int pos = atomicAdd(&cursor[n], 1);
        csr_src[pos] = n;
    }
}

// ---------------- weight transpose+cast: WT[n*K+k] = bf16(W[k*N+n]) ----------------
__global__ void transpose_cast(const float* __restrict__ W, unsigned short* __restrict__ WT,
                               int K, int N) {
    int idx = blockIdx.x * blockDim.x + threadIdx.x;
    if (idx < K * N) {
        int n = idx / K, k = idx - n * K;
        WT[idx] = f2b(W[(size_t)k * N + n]);
    }
}

// ---------------- features + layernorm (bf16 out), wave-per-node ----------------
__global__ void feat_ln(const float* __restrict__ xs,
                        const int* __restrict__ xo, const int* __restrict__ xsrc,
                        const int* __restrict__ xsink, const int* __restrict__ xstr,
                        const int* __restrict__ xpay,
                        const float* __restrict__ eo, const float* __restrict__ es,
                        const float* __restrict__ ek, const float* __restrict__ eg,
                        const float* __restrict__ ep,
                        const float* __restrict__ lns, const float* __restrict__ lnb,
                        unsigned short* __restrict__ x0) {
    int node = blockIdx.x * 4 + (threadIdx.x >> 6);
    if (node >= N_NODES) return;
    int lane = threadIdx.x & 63;
    int c = lane * 4;                 // 4 contiguous channels per lane; lanes 56-63 idle
    float f0 = 0.f, f1 = 0.f, f2 = 0.f, f3 = 0.f;
    if (lane < 16) {
        float4 v = *reinterpret_cast<const float4*>(&xs[(size_t)node * S_SCAL + c]);
        f0 = v.x; f1 = v.y; f2 = v.z; f3 = v.w;
    } else if (lane < 56) {
        int t = c - S_SCAL;           // 0..159
        int ti = t >> 5, dim = t & 31;
        const int* idx; const float* emb;
        switch (ti) {
            case 0: idx = xo;   emb = eo; break;
            case 1: idx = xsrc; emb = es; break;
            case 2: idx = xsink;emb = ek; break;
            case 3: idx = xstr; emb = eg; break;
            default:idx = xpay; emb = ep; break;
        }
        float a0 = 0.f, a1 = 0.f, a2 = 0.f, a3 = 0.f, cnt = 0.f;
        #pragma unroll
        for (int l = 0; l < L_TOK; ++l) {
            int id = idx[node * L_TOK + l];
            if (id != 0) {
                float4 e = *reinterpret_cast<const float4*>(&emb[id * D_EMB + dim]);
                a0 += e.x; a1 += e.y; a2 += e.z; a3 += e.w; cnt += 1.f;
            }
        }
        float r = 1.f / (cnt + 1e-9f);
        f0 = a0 * r; f1 = a1 * r; f2 = a2 * r; f3 = a3 * r;
    }
    float s = f0 + f1 + f2 + f3;
    float q = f0 * f0 + f1 * f1 + f2 * f2 + f3 * f3;
    #pragma unroll
    for (int off = 32; off; off >>= 1) {
        s += __shfl_xor(s, off);
        q += __shfl_xor(q, off);
    }
    float mu = s * (1.f / (float)TOT);
    float var = q * (1.f / (float)TOT) - mu * mu;
    float rs = rsqrtf(var + 1e-5f);
    if (lane < 56) {
        float4 sc = *reinterpret_cast<const float4*>(&lns[c]);
        float4 bi = *reinterpret_cast<const float4*>(&lnb[c]);
        ushort4 o;
        o.x = f2b((f0 - mu) * rs * sc.x + bi.x);
        o.y = f2b((f1 - mu) * rs * sc.y + bi.y);
        o.z = f2b((f2 - mu) * rs * sc.z + bi.z);
        o.w = f2b((f3 - mu) * rs * sc.w + bi.w);
        *reinterpret_cast<ushort4*>(&x0[(size_t)node * TOT + c]) = o;
    }
}

// ---------------- bf16 MFMA GEMM: C[M,N] = A[M,K] @ BT[N,K]^T ----------------
// BM=BN=64, BK=32, 256 threads (4 waves), mfma_f32_16x16x32_bf16.
__global__ void gemm_bf16(const unsigned short* __restrict__ A,
                          const unsigned short* __restrict__ BT,
                          unsigned short* __restrict__ C, int M, int N, int K) {
    __shared__ unsigned short As[64][40];   // 32 k + 8 pad
    __shared__ unsigned short Bs[64][40];
    int tid = threadIdx.x;
    int wave = tid >> 6, lane = tid & 63;
    int l15 = lane & 15, kb = lane >> 4;    // kb in 0..3
    int bm = blockIdx.x * 64, bn = blockIdx.y * 64;
    f32x4 acc[4] = {};
    int row_ld = tid >> 2, seg = tid & 3;
    for (int k0 = 0; k0 < K; k0 += 32) {
        {
            const uint4 v = *reinterpret_cast<const uint4*>(&A[(size_t)(bm + row_ld) * K + k0 + seg * 8]);
            *reinterpret_cast<uint4*>(&As[row_ld][seg * 8]) = v;
        }
        {
            const uint4 v = *reinterpret_cast<const uint4*>(&BT[(size_t)(bn + row_ld) * K + k0 + seg * 8]);
            *reinterpret_cast<uint4*>(&Bs[row_ld][seg * 8]) = v;
        }
        __syncthreads();
        bf16x8 af = *reinterpret_cast<const bf16x8*>(&As[wave * 16 + l15][kb * 8]);
        #pragma unroll
        for (int t = 0; t < 4; ++t) {
            bf16x8 bfr = *reinterpret_cast<const bf16x8*>(&Bs[t * 16 + l15][kb * 8]);
            acc[t] = __builtin_amdgcn_mfma_f32_16x16x32_bf16(af, bfr, acc[t], 0, 0, 0);
        }
        __syncthreads();
    }
    #pragma unroll
    for (int t = 0; t < 4; ++t) {
        #pragma unroll
        for (int r = 0; r < 4; ++r) {
            int row = bm + wave * 16 + kb * 4 + r;
            if (row < M)
                C[(size_t)row * N + bn + t * 16 + l15] = f2b(acc[t][r]);
        }
    }
}

// ---------------- attention prep ----------------
__global__ void att_prep1(const unsigned short* __restrict__ h1, const float* __restrict__ asrc,
                          const float* __restrict__ adst, float* __restrict__ s1,
                          float* __restrict__ d1) {
    int n = blockIdx.x, tid = threadIdx.x;  // 512 threads
    float h = b2f(h1[(size_t)n * F1 + tid]);
    float sv = h * asrc[tid], dv = h * adst[tid];
    for (int off = 32; off; off >>= 1) { sv += __shfl_down(sv, off); dv += __shfl_down(dv, off); }
    __shared__ float ssh[8], dsh[8];
    if ((tid & 63) == 0) { ssh[tid >> 6] = sv; dsh[tid >> 6] = dv; }
    __syncthreads();
    if (tid < H1) {
        s1[n * H1 + tid] = ssh[2 * tid] + ssh[2 * tid + 1];
        d1[n * H1 + tid] = dsh[2 * tid] + dsh[2 * tid + 1];
    }
}

__global__ void att_prep2(const unsigned short* __restrict__ h2, const float* __restrict__ asrc,
                          const float* __restrict__ adst, float* __restrict__ s2,
                          float* __restrict__ d2) {
    int n = blockIdx.x, tid = threadIdx.x;  // 128 threads
    float h = b2f(h2[(size_t)n * F2 + tid]);
    float sv = h * asrc[tid], dv = h * adst[tid];
    for (int off = 32; off; off >>= 1) { sv += __shfl_down(sv, off); dv += __shfl_down(dv, off); }
    __shared__ float ssh[2], dsh[2];
    if ((tid & 63) == 0) { ssh[tid >> 6] = sv; dsh[tid >> 6] = dv; }
    __syncthreads();
    if (tid == 0) { s2[n] = ssh[0] + ssh[1]; d2[n] = dsh[0] + dsh[1]; }
}

// ---------------- GAT layer 1: softmax + aggregate + bias + elu ----------------
__global__ void gat1_aggregate(const unsigned short* __restrict__ h1, const float* __restrict__ s1,
                               const float* __restrict__ d1, const int* __restrict__ rowptr,
                               const int* __restrict__ csr, const float* __restrict__ b1,
                               unsigned short* __restrict__ x1) {
    int n = blockIdx.x, tid = threadIdx.x;    // 256 threads; wave = head for phases 1-2
    int wave = tid >> 6, lane = tid & 63;
    int r0 = rowptr[n], deg = rowptr[n + 1] - r0;
    __shared__ float m_sh[H1], den_sh[H1], d_n[H1];
    __shared__ float alpha_sh[H1][64];
    __shared__ int src_sh[64];
    if (tid < H1) d_n[tid] = d1[n * H1 + tid];
    __syncthreads();
    float dnw = d_n[wave];
    float m = -1e30f;
    for (int i = lane; i < deg; i += 64) {
        int src = csr[r0 + i];
        float e = s1[src * H1 + wave] + dnw;
        e = (e >= 0.f) ? e : 0.2f * e;
        m = fmaxf(m, e);
    }
    for (int off = 32; off; off >>= 1) m = fmaxf(m, __shfl_down(m, off));
    if (lane == 0) m_sh[wave] = m;
    __syncthreads();
    float mh = m_sh[wave];
    float den = 0.f;
    for (int i = lane; i < deg; i += 64) {
        int src = csr[r0 + i];
        float e = s1[src * H1 + wave] + dnw;
        e = (e >= 0.f) ? e : 0.2f * e;
        den += __expf(e - mh);
    }
    for (int off = 32; off; off >>= 1) den += __shfl_down(den, off);
    if (lane == 0) den_sh[wave] = den;
    __syncthreads();
    float invw = 1.f / den_sh[wave];
    const unsigned* h1u = (const unsigned*)h1;   // rows of 256 uints
    float2 acc = make_float2(0.f, 0.f);
    for (int c0 = 0; c0 < deg; c0 += 64) {
        __syncthreads();
        int i = c0 + lane;
        if (i < deg) {
            int src = csr[r0 + i];
            if (wave == 0) src_sh[lane] = src;
            float e = s1[src * H1 + wave] + dnw;
            e = (e >= 0.f) ? e : 0.2f * e;
            alpha_sh[wave][lane] = __expf(e - mh) * invw;
        }
        __syncthreads();
        int cnt = min(64, deg - c0);
        int hh = tid >> 6;
        for (int e = 0; e < cnt; ++e) {
            int src = src_sh[e];
            float a = alpha_sh[hh][e];
            unsigned v = h1u[(size_t)src * 256 + tid];
            acc.x += a * b2f((unsigned short)(v & 0xFFFFu));
            acc.y += a * b2f((unsigned short)(v >> 16));
        }
    }
    int c = 2 * tid;
    float v0 = acc.x + b1[c];     v0 = (v0 > 0.f) ? v0 : expm1f(v0);
    float v1 = acc.y + b1[c + 1]; v1 = (v1 > 0.f) ? v1 : expm1f(v1);
    unsigned packed = (unsigned)f2b(v0) | ((unsigned)f2b(v1) << 16);
    ((unsigned*)x1)[(size_t)n * 256 + tid] = packed;
}

// ---------------- GAT layer 2 + elu + graph max-pool ----------------
__device__ __forceinline__ unsigned int f2ord(float f) {
    unsigned int b = __float_as_uint(f);
    return (b & 0x80000000u) ? ~b : (b | 0x80000000u);
}

__global__ void pool_init(unsigned int* pool) {
    int i = blockIdx.x * blockDim.x + threadIdx.x;
    if (i < N_GRAPH * F2) pool[i] = 0x007FFFFFu;   // f2ord(-inf)
}

__global__ void gat2_pool(const unsigned short* __restrict__ h2, const float* __restrict__ s2,
                          const float* __restrict__ d2, const int* __restrict__ rowptr,
                          const int* __restrict__ csr, const float* __restrict__ b2,
                          const int* __restrict__ batch, unsigned int* __restrict__ pool) {
    int n = blockIdx.x, tid = threadIdx.x;   // 128 threads
    int r0 = rowptr[n], deg = rowptr[n + 1] - r0;
    __shared__ float sh[2];
    __shared__ float m_s, den_s;
    __shared__ float alpha_sh[128];
    __shared__ int src_sh[128];
    float dn = d2[n];
    float m = -1e30f;
    for (int i = tid; i < deg; i += 128) {
        float e = s2[csr[r0 + i]] + dn; e = (e >= 0.f) ? e : 0.2f * e;
        m = fmaxf(m, e);
    }
    for (int off = 32; off; off >>= 1) m = fmaxf(m, __shfl_down(m, off));
    if ((tid & 63) == 0) sh[tid >> 6] = m;
    __syncthreads();
    if (tid == 0) m_s = fmaxf(sh[0], sh[1]);
    __syncthreads();
    float mm = m_s;
    float den = 0.f;
    for (int i = tid; i < deg; i += 128) {
        float e = s2[csr[r0 + i]] + dn; e = (e >= 0.f) ? e : 0.2f * e;
        den += __expf(e - mm);
    }
    for (int off = 32; off; off >>= 1) den += __shfl_down(den, off);
    if ((tid & 63) == 0) sh[tid >> 6] = den;
    __syncthreads();
    if (tid == 0) den_s = sh[0] + sh[1];
    __syncthreads();
    float inv = 1.f / den_s;
    float acc = 0.f;
    for (int c0 = 0; c0 < deg; c0 += 128) {
        __syncthreads();
        int i = c0 + tid;
        if (i < deg) {
            int src = csr[r0 + i];
            src_sh[tid] = src;
            float e = s2[src] + dn; e = (e >= 0.f) ? e : 0.2f * e;
            alpha_sh[tid] = __expf(e - mm) * inv;
        }
        __syncthreads();
        int cnt = min(128, deg - c0);
        for (int e = 0; e < cnt; ++e)
            acc += alpha_sh[e] * b2f(h2[(size_t)src_sh[e] * F2 + tid]);
    }
    float v = acc + b2[tid];
    v = (v > 0.f) ? v : expm1f(v);
    atomicMax(&pool[batch[n] * F2 + tid], f2ord(v));
}

__global__ void pool_finalize(const unsigned int* __restrict__ pool, float* __restrict__ out) {
    int i = blockIdx.x * blockDim.x + threadIdx.x;
    if (i < N_GRAPH * F2) {
        unsigned int k = pool[i];
        unsigned int b = (k & 0x80000000u) ? (k ^ 0x80000000u) : ~k;
        out[i] = __uint_as_float(b);
    }
}

// ---------------- launcher ----------------
extern "C" void kernel_launch(void* const* d_in, const int* in_sizes, int n_in,
                              void* d_out, int out_size, void* d_ws, size_t ws_size,
                              hipStream_t stream) {
    const float* x_scalar = (const float*)d_in[0];
    const int*   x_opcode = (const int*)d_in[1];
    const int*   x_source = (const int*)d_in[2];
    const int*   x_sink   = (const int*)d_in[3];
    const int*   x_string = (const int*)d_in[4];
    const int*   x_payload= (const int*)d_in[5];
    const int*   edge_idx = (const int*)d_in[6];
    const int*   batch    = (const int*)d_in[7];
    const float* emb_op   = (const float*)d_in[8];
    const float* emb_src  = (const float*)d_in[9];
    const float* emb_snk  = (const float*)d_in[10];
    const float* emb_str  = (const float*)d_in[11];
    const float* emb_pay  = (const float*)d_in[12];
    const float* ln_scale = (const float*)d_in[13];
    const float* ln_bias  = (const float*)d_in[14];
    const float* W1       = (const float*)d_in[15];
    const float* att_src1 = (const float*)d_in[16];
    const float* att_dst1 = (const float*)d_in[17];
    const float* b1       = (const float*)d_in[18];
    const float* W2       = (const float*)d_in[19];
    const float* att_src2 = (const float*)d_in[20];
    const float* att_dst2 = (const float*)d_in[21];
    const float* b2       = (const float*)d_in[22];
    float* out = (float*)d_out;

    // workspace layout
    unsigned short* x0  = (unsigned short*)d_ws;               // M_PAD*224 bf16
    unsigned short* h1  = x0 + (size_t)M_PAD * TOT;            // M_PAD*512
    unsigned short* x1  = h1 + (size_t)M_PAD * F1;             // M_PAD*512
    unsigned short* h2  = x1 + (size_t)M_PAD * F1;             // M_PAD*128
    unsigned short* W1T = h2 + (size_t)M_PAD * F2;             // 512*224
    unsigned short* W2T = W1T + (size_t)F1 * TOT;              // 128*512
    float* s1 = (float*)(W2T + (size_t)F2 * F1);               // N*4
    float* d1 = s1 + (size_t)N_NODES * H1;
    float* s2 = d1 + (size_t)N_NODES * H1;                     // N
    float* d2 = s2 + N_NODES;
    int* rowptr = (int*)(d2 + N_NODES);                        // N+1
    int* cursor = rowptr + (N_NODES + 1);                      // N+1
    int* csr    = cursor + (N_NODES + 1);                      // E_TOT
    unsigned int* pool = (unsigned int*)(csr + E_TOT);         // G*128

    // CSR build
    init_deg<<<(N_NODES + 255) / 256, 256, 0, stream>>>(cursor);
    add_deg<<<(N_EDGES + 255) / 256, 256, 0, stream>>>(edge_idx, cursor);
    scan_deg<<<1, 1024, 0, stream>>>(cursor, rowptr, cursor);
    scatter_edges<<<(E_TOT + 255) / 256, 256, 0, stream>>>(edge_idx, cursor, csr);

    // weight transposes
    transpose_cast<<<(TOT * F1 + 255) / 256, 256, 0, stream>>>(W1, W1T, TOT, F1);
    transpose_cast<<<(F1 * F2 + 255) / 256, 256, 0, stream>>>(W2, W2T, F1, F2);

    // features + LN (wave per node, 4 nodes/block)
    feat_ln<<<(N_NODES + 3) / 4, 256, 0, stream>>>(x_scalar, x_opcode, x_source, x_sink,
                                                   x_string, x_payload, emb_op, emb_src,
                                                   emb_snk, emb_str, emb_pay, ln_scale,
                                                   ln_bias, x0);

    // layer 1
    dim3 g1(M_PAD / 64, F1 / 64);
    gemm_bf16<<<g1, 256, 0, stream>>>(x0, W1T, h1, N_NODES, F1, TOT);
    att_prep1<<<N_NODES, 512, 0, stream>>>(h1, att_src1, att_dst1, s1, d1);
    gat1_aggregate<<<N_NODES, 256, 0, stream>>>(h1, s1, d1, rowptr, csr, b1, x1);

    // layer 2
    dim3 g2(M_PAD / 64, F2 / 64);
    gemm_bf16<<<g2, 256, 0, stream>>>(x1, W2T, h2, N_NODES, F2, F1);
    att_prep2<<<N_NODES, 128, 0, stream>>>(h2, att_src2, att_dst2, s2, d2);

    pool_init<<<(N_GRAPH * F2 + 255) / 256, 256, 0, stream>>>(pool);
    gat2_pool<<<N_NODES, 128, 0, stream>>>(h2, s2, d2, rowptr, csr, b2, batch, pool);
    pool_finalize<<<(N_GRAPH * F2 + 255) / 256, 256, 0, stream>>>(pool, out);
}